// Round 1
// baseline (145.035 us; speedup 1.0000x reference)
//
#include <hip/hip_runtime.h>
#include <math.h>

#define NUM_CLASSES 80
#define TB 64   // targets per image
#define NB 8    // batch

// Single compiled copy called from both pass1 and pass2 so IoU values are
// bit-identical across kernels (required for the `iou == gt_max` exact
// equality in the low-quality-match logic).
__device__ __attribute__((noinline)) float iou_fn(
    float bx0, float by0, float bx1, float by1,   // gt box (xyxy)
    float ax0, float ay0, float ax1, float ay1) { // anchor (xyxy)
  float area_t = (bx1 - bx0) * (by1 - by0);
  float area_a = (ax1 - ax0) * (ay1 - ay0);
  // block fp-contraction so area/intersection products aren't fused into the
  // denominator add differently from the numpy reference
  asm volatile("" : "+v"(area_t));
  asm volatile("" : "+v"(area_a));
  float ltx = fmaxf(bx0, ax0);
  float lty = fmaxf(by0, ay0);
  float rbx = fminf(bx1, ax1);
  float rby = fminf(by1, ay1);
  float w = fmaxf(rbx - ltx, 0.0f);
  float h = fmaxf(rby - lty, 0.0f);
  float inter = w * h;
  asm volatile("" : "+v"(inter));
  return inter / (area_t + area_a - inter);
}

// pass 0: cxcywh -> xyxy once (shared, bit-identical source for both passes);
// zero gt_max (IoU >= 0 so 0 is the identity for max)
__global__ void pass0(const float* __restrict__ tgt,
                      float* __restrict__ boxes_xyxy,
                      float* __restrict__ gmax) {
  int i = blockIdx.x * blockDim.x + threadIdx.x;
  if (i < NB * TB) {
    float cx = tgt[i * 4 + 0], cy = tgt[i * 4 + 1];
    float w  = tgt[i * 4 + 2], h  = tgt[i * 4 + 3];
    boxes_xyxy[i * 4 + 0] = cx - 0.5f * w;
    boxes_xyxy[i * 4 + 1] = cy - 0.5f * h;
    boxes_xyxy[i * 4 + 2] = cx + 0.5f * w;
    boxes_xyxy[i * 4 + 3] = cy + 0.5f * h;
    gmax[i] = 0.0f;
  }
}

// pass 1: gt_max[b][t] = max_a IoU(t, a).  blockIdx = (anchor-chunk, b, t).
#define P1_APB 2048  // anchors per block (256 threads x 8)
__global__ void pass1(const float* __restrict__ anchors,
                      const float* __restrict__ boxes,
                      float* __restrict__ gmax, int A) {
  int b = blockIdx.y, t = blockIdx.z;
  const float* bp = boxes + (b * TB + t) * 4;
  float b0 = bp[0], b1 = bp[1], b2 = bp[2], b3 = bp[3];
  int base = blockIdx.x * P1_APB + threadIdx.x;
  float best = 0.0f;
  for (int k = 0; k < 8; ++k) {
    int a = base + k * 256;
    if (a < A) {
      float ax0 = anchors[a * 4 + 0], ay0 = anchors[a * 4 + 1];
      float ax1 = anchors[a * 4 + 2], ay1 = anchors[a * 4 + 3];
      best = fmaxf(best, iou_fn(b0, b1, b2, b3, ax0, ay0, ax1, ay1));
    }
  }
  // wave (64-lane) reduce, then cross-wave via LDS
  for (int off = 32; off > 0; off >>= 1)
    best = fmaxf(best, __shfl_down(best, off, 64));
  __shared__ float s[4];
  int lane = threadIdx.x & 63, wid = threadIdx.x >> 6;
  if (lane == 0) s[wid] = best;
  __syncthreads();
  if (threadIdx.x == 0) {
    float m = fmaxf(fmaxf(s[0], s[1]), fmaxf(s[2], s[3]));
    // IoU >= 0 -> float bit pattern order == int order
    atomicMax((int*)(gmax + b * TB + t), __float_as_int(m));
  }
}

// pass 2: per (b, anchor): argmax over t, thresholds, low-quality flag,
// label + deltas.
__global__ void pass2(const float* __restrict__ anchors,
                      const float* __restrict__ boxes,
                      const float* __restrict__ gmax,
                      const int* __restrict__ labels,
                      float* __restrict__ out, int A) {
  int b = blockIdx.y;
  __shared__ float sb[TB * 4];
  __shared__ float sg[TB];
  __shared__ int   sl[TB];
  int tid = threadIdx.x;
  if (tid < TB) {
    sg[tid] = gmax[b * TB + tid];
    sl[tid] = labels[b * TB + tid];
  }
  for (int i = tid; i < TB * 4; i += 256) sb[i] = boxes[b * TB * 4 + i];
  __syncthreads();

  int a = blockIdx.x * 256 + tid;
  if (a >= A) return;
  float ax0 = anchors[a * 4 + 0], ay0 = anchors[a * 4 + 1];
  float ax1 = anchors[a * 4 + 2], ay1 = anchors[a * 4 + 3];

  float best = -1.0f;
  int mid = 0;
  bool high = false;
  for (int t = 0; t < TB; ++t) {
    float v = iou_fn(sb[t * 4 + 0], sb[t * 4 + 1], sb[t * 4 + 2], sb[t * 4 + 3],
                     ax0, ay0, ax1, ay1);
    if (v > best) { best = v; mid = t; }  // strict > == argmax first-occurrence
    high = high || (v == sg[t]);
  }

  int lab;
  if (high)             lab = 1;   // low-quality matches become positives
  else if (best >= 0.5f) lab = 1;
  else if (best >= 0.4f) lab = -1;
  else                   lab = 0;

  int out_label;
  if (lab == 1)      out_label = sl[mid];
  else if (lab == 0) out_label = NUM_CLASSES;
  else               out_label = -1;

  out[(size_t)b * A + a] = (float)out_label;

  // deltas vs matched box
  float bx0 = sb[mid * 4 + 0], by0 = sb[mid * 4 + 1];
  float bx1 = sb[mid * 4 + 2], by1 = sb[mid * 4 + 3];
  float sw = ax1 - ax0, sh = ay1 - ay0;
  float sx = ax0 + 0.5f * sw, sy = ay0 + 0.5f * sh;
  float tw = bx1 - bx0, th = by1 - by0;
  float tx = bx0 + 0.5f * tw, ty = by0 + 0.5f * th;
  float4 d;
  d.x = (tx - sx) / sw;
  d.y = (ty - sy) / sh;
  d.z = logf(tw / sw);
  d.w = logf(th / sh);
  *(float4*)(out + (size_t)NB * A + ((size_t)b * A + a) * 4) = d;
}

extern "C" void kernel_launch(void* const* d_in, const int* in_sizes, int n_in,
                              void* d_out, int out_size, void* d_ws, size_t ws_size,
                              hipStream_t stream) {
  const float* anchors    = (const float*)d_in[0];
  const float* tgt_boxes  = (const float*)d_in[1];
  const int*   tgt_labels = (const int*)d_in[2];
  int A = in_sizes[0] / 4;

  float* ws    = (float*)d_ws;
  float* boxes = ws;                 // NB*TB*4 floats
  float* gmax  = ws + NB * TB * 4;   // NB*TB floats
  float* out   = (float*)d_out;

  pass0<<<2, 256, 0, stream>>>(tgt_boxes, boxes, gmax);
  dim3 g1((A + P1_APB - 1) / P1_APB, NB, TB);
  pass1<<<g1, 256, 0, stream>>>(anchors, boxes, gmax, A);
  dim3 g2((A + 255) / 256, NB);
  pass2<<<g2, 256, 0, stream>>>(anchors, boxes, gmax, tgt_labels, out, A);
}

// Round 2
// 120.834 us; speedup vs baseline: 1.2003x; 1.2003x over previous
//
#include <hip/hip_runtime.h>
#include <math.h>

// All IoU arithmetic must be bit-identical between pass1 and pass2 (the
// low-quality-match logic does an exact `iou == gt_max` compare). With fp
// contraction off, every op below is an exactly-rounded IEEE op in a fixed
// order -> identical results in both kernels even when fully inlined.
#pragma clang fp contract(off)

#define NUM_CLASSES 80
#define TB 64   // targets per image
#define NB 8    // batch

// pass 0: cxcywh -> xyxy once + gt-box area + zero gt_max
__global__ void pass0(const float* __restrict__ tgt,
                      float* __restrict__ boxes_xyxy,
                      float* __restrict__ areas,
                      float* __restrict__ gmax) {
  int i = blockIdx.x * blockDim.x + threadIdx.x;
  if (i < NB * TB) {
    float cx = tgt[i * 4 + 0], cy = tgt[i * 4 + 1];
    float w  = tgt[i * 4 + 2], h  = tgt[i * 4 + 3];
    float x0 = cx - 0.5f * w, y0 = cy - 0.5f * h;
    float x1 = cx + 0.5f * w, y1 = cy + 0.5f * h;
    boxes_xyxy[i * 4 + 0] = x0;
    boxes_xyxy[i * 4 + 1] = y0;
    boxes_xyxy[i * 4 + 2] = x1;
    boxes_xyxy[i * 4 + 3] = y1;
    areas[i] = (x1 - x0) * (y1 - y0);
    gmax[i] = 0.0f;  // IoU >= 0, so 0 is the max-identity
  }
}

// pass 1: gt_max[b][t] = max_a IoU(t, a).
// block = 256 threads x 8 anchors in registers; loop t over LDS boxes.
#define P1_APB 2048  // anchors per block
__global__ void pass1(const float* __restrict__ anchors,
                      const float* __restrict__ boxes,
                      const float* __restrict__ areas,
                      float* __restrict__ gmax, int A) {
  int b = blockIdx.y;
  __shared__ float4 sb[TB];
  __shared__ float  sa[TB];
  __shared__ int    sg[TB];
  int tid = threadIdx.x;
  if (tid < TB) {
    sb[tid] = ((const float4*)boxes)[b * TB + tid];
    sa[tid] = areas[b * TB + tid];
    sg[tid] = 0;
  }
  __syncthreads();

  // 8 anchors per thread, resident in registers (clamped dup is benign for max)
  float ax0[8], ay0[8], ax1[8], ay1[8], aar[8];
  int base = blockIdx.x * P1_APB + tid;
#pragma unroll
  for (int k = 0; k < 8; ++k) {
    int a = base + k * 256;
    if (a > A - 1) a = A - 1;
    float4 av = ((const float4*)anchors)[a];
    ax0[k] = av.x; ay0[k] = av.y; ax1[k] = av.z; ay1[k] = av.w;
    aar[k] = (av.z - av.x) * (av.w - av.y);
  }

#pragma unroll 4
  for (int t = 0; t < TB; ++t) {
    float4 bb = sb[t];          // block-uniform -> LDS broadcast, no conflict
    float at = sa[t];
    float m = 0.0f;
#pragma unroll
    for (int k = 0; k < 8; ++k) {
      float ltx = fmaxf(bb.x, ax0[k]);
      float lty = fmaxf(bb.y, ay0[k]);
      float rbx = fminf(bb.z, ax1[k]);
      float rby = fminf(bb.w, ay1[k]);
      float w = fmaxf(rbx - ltx, 0.0f);
      float h = fmaxf(rby - lty, 0.0f);
      float inter = w * h;
      float v = inter / ((at + aar[k]) - inter);
      m = fmaxf(m, v);
    }
    // 64-lane wave max-reduce
    for (int off = 32; off > 0; off >>= 1)
      m = fmaxf(m, __shfl_down(m, off, 64));
    if ((tid & 63) == 0)
      atomicMax(&sg[t], __float_as_int(m));  // IoU >= 0: int order == float order
  }
  __syncthreads();
  if (tid < TB)
    atomicMax((int*)(gmax + b * TB + tid), sg[tid]);
}

// pass 2: per (b, anchor): argmax over t, thresholds, low-quality flag,
// label + deltas.
__global__ void pass2(const float* __restrict__ anchors,
                      const float* __restrict__ boxes,
                      const float* __restrict__ areas,
                      const float* __restrict__ gmax,
                      const int* __restrict__ labels,
                      float* __restrict__ out, int A) {
  int b = blockIdx.y;
  __shared__ float4 sb[TB];
  __shared__ float  sa[TB];
  __shared__ float  sg[TB];
  __shared__ int    sl[TB];
  int tid = threadIdx.x;
  if (tid < TB) {
    sb[tid] = ((const float4*)boxes)[b * TB + tid];
    sa[tid] = areas[b * TB + tid];
    sg[tid] = gmax[b * TB + tid];
    sl[tid] = labels[b * TB + tid];
  }
  __syncthreads();

  int a = blockIdx.x * 256 + tid;
  if (a >= A) return;
  float4 av = ((const float4*)anchors)[a];
  float aarea = (av.z - av.x) * (av.w - av.y);

  float best = -1.0f;
  int mid = 0;
  bool high = false;
#pragma unroll 4
  for (int t = 0; t < TB; ++t) {
    float4 bb = sb[t];
    float ltx = fmaxf(bb.x, av.x);
    float lty = fmaxf(bb.y, av.y);
    float rbx = fminf(bb.z, av.z);
    float rby = fminf(bb.w, av.w);
    float w = fmaxf(rbx - ltx, 0.0f);
    float h = fmaxf(rby - lty, 0.0f);
    float inter = w * h;
    float v = inter / ((sa[t] + aarea) - inter);
    if (v > best) { best = v; mid = t; }  // strict > == argmax first-occurrence
    high = high || (v == sg[t]);
  }

  int lab;
  if (high)              lab = 1;   // low-quality matches become positives
  else if (best >= 0.5f) lab = 1;
  else if (best >= 0.4f) lab = -1;
  else                   lab = 0;

  int out_label;
  if (lab == 1)      out_label = sl[mid];
  else if (lab == 0) out_label = NUM_CLASSES;
  else               out_label = -1;

  out[(size_t)b * A + a] = (float)out_label;

  // deltas vs matched box
  float4 mb = sb[mid];
  float sw = av.z - av.x, sh = av.w - av.y;
  float sx = av.x + 0.5f * sw, sy = av.y + 0.5f * sh;
  float tw = mb.z - mb.x, th = mb.w - mb.y;
  float tx = mb.x + 0.5f * tw, ty = mb.y + 0.5f * th;
  float4 d;
  d.x = (tx - sx) / sw;
  d.y = (ty - sy) / sh;
  d.z = logf(tw / sw);
  d.w = logf(th / sh);
  *(float4*)(out + (size_t)NB * A + ((size_t)b * A + a) * 4) = d;
}

extern "C" void kernel_launch(void* const* d_in, const int* in_sizes, int n_in,
                              void* d_out, int out_size, void* d_ws, size_t ws_size,
                              hipStream_t stream) {
  const float* anchors    = (const float*)d_in[0];
  const float* tgt_boxes  = (const float*)d_in[1];
  const int*   tgt_labels = (const int*)d_in[2];
  int A = in_sizes[0] / 4;

  float* ws    = (float*)d_ws;
  float* boxes = ws;                       // NB*TB*4 floats
  float* areas = ws + NB * TB * 4;         // NB*TB floats
  float* gmax  = ws + NB * TB * 5;         // NB*TB floats
  float* out   = (float*)d_out;

  pass0<<<2, 256, 0, stream>>>(tgt_boxes, boxes, areas, gmax);
  dim3 g1((A + P1_APB - 1) / P1_APB, NB);
  pass1<<<g1, 256, 0, stream>>>(anchors, boxes, areas, gmax, A);
  dim3 g2((A + 255) / 256, NB);
  pass2<<<g2, 256, 0, stream>>>(anchors, boxes, areas, gmax, tgt_labels, out, A);
}

// Round 3
// 111.122 us; speedup vs baseline: 1.3052x; 1.0874x over previous
//
#include <hip/hip_runtime.h>
#include <math.h>

// All IoU arithmetic must be bit-identical between pass1 and pass2 (the
// low-quality-match logic does an exact `iou == gt_max` compare). With fp
// contraction off, every op is an exactly-rounded IEEE op in a fixed order
// -> identical results in both kernels even when fully inlined.
#pragma clang fp contract(off)

#define NUM_CLASSES 80
#define TB 64   // targets per image
#define NB 8    // batch

// rocPRIM-style gfx9 wave64 max-reduce on DPP (pure VALU, no LDS pipe).
// Valid for non-negative x (bound_ctrl=1 feeds 0.0f to OOB lanes).
// Full max ends up in lane 63.
__device__ __forceinline__ float wave_max_nonneg(float x) {
  int v = __float_as_int(x);
#define DPPMAX(ctrl)                                                         \
  v = __float_as_int(fmaxf(__int_as_float(v),                               \
      __int_as_float(__builtin_amdgcn_update_dpp(0, v, ctrl, 0xf, 0xf, true))));
  DPPMAX(0x111);  // row_shr:1
  DPPMAX(0x112);  // row_shr:2
  DPPMAX(0x114);  // row_shr:4
  DPPMAX(0x118);  // row_shr:8
  DPPMAX(0x142);  // row_bcast:15
  DPPMAX(0x143);  // row_bcast:31
#undef DPPMAX
  return __int_as_float(v);
}

// pass 0: cxcywh -> xyxy + gt-box area; zero gmax slot (IoU >= 0).
__global__ void pass0(const float* __restrict__ tgt,
                      float4* __restrict__ boxes,
                      float2* __restrict__ ag) {
  int i = blockIdx.x * blockDim.x + threadIdx.x;
  if (i < NB * TB) {
    float cx = tgt[i * 4 + 0], cy = tgt[i * 4 + 1];
    float w  = tgt[i * 4 + 2], h  = tgt[i * 4 + 3];
    float x0 = cx - 0.5f * w, y0 = cy - 0.5f * h;
    float x1 = cx + 0.5f * w, y1 = cy + 0.5f * h;
    boxes[i] = make_float4(x0, y0, x1, y1);
    ag[i] = make_float2((x1 - x0) * (y1 - y0), 0.0f);  // {area, gmax=0}
  }
}

// pass 1: gmax[b][t] = max_a IoU(t, a).
// K=4 anchors/thread in registers, t-range split over blockIdx.z for occupancy.
#define P1_K 4
#define P1_APB (P1_K * 256)   // anchors per block
#define P1_TSPLIT 2
#define P1_TCHUNK (TB / P1_TSPLIT)
__global__ __launch_bounds__(256) void pass1(const float4* __restrict__ anchors,
                                             const float4* __restrict__ boxes,
                                             const float2* __restrict__ ag,
                                             int* __restrict__ agbits,
                                             int A) {
  int b = blockIdx.y;
  int t0 = blockIdx.z * P1_TCHUNK;
  __shared__ float4 sb[P1_TCHUNK];
  __shared__ float  sa[P1_TCHUNK];
  __shared__ int    ssg[P1_TCHUNK];
  int tid = threadIdx.x;
  if (tid < P1_TCHUNK) {
    sb[tid]  = boxes[b * TB + t0 + tid];
    sa[tid]  = ag[b * TB + t0 + tid].x;
    ssg[tid] = 0;
  }
  __syncthreads();

  float ax0[P1_K], ay0[P1_K], ax1[P1_K], ay1[P1_K], aar[P1_K];
  int base = blockIdx.x * P1_APB + tid;
#pragma unroll
  for (int k = 0; k < P1_K; ++k) {
    int a = base + k * 256;
    if (a > A - 1) a = A - 1;  // clamped dup is benign for max
    float4 av = anchors[a];
    ax0[k] = av.x; ay0[k] = av.y; ax1[k] = av.z; ay1[k] = av.w;
    aar[k] = (av.z - av.x) * (av.w - av.y);
  }

#pragma unroll 4
  for (int t = 0; t < P1_TCHUNK; ++t) {
    float4 bb = sb[t];   // block-uniform -> LDS broadcast
    float at = sa[t];
    float m = 0.0f;
#pragma unroll
    for (int k = 0; k < P1_K; ++k) {
      float w = fmaxf(fminf(bb.z, ax1[k]) - fmaxf(bb.x, ax0[k]), 0.0f);
      float h = fmaxf(fminf(bb.w, ay1[k]) - fmaxf(bb.y, ay0[k]), 0.0f);
      float inter = w * h;
      float v = inter / ((at + aar[k]) - inter);
      m = fmaxf(m, v);
    }
    m = wave_max_nonneg(m);   // result in lane 63
    if ((tid & 63) == 63)
      atomicMax(&ssg[t], __float_as_int(m));  // IoU>=0: int order == float order
  }
  __syncthreads();
  if (tid < P1_TCHUNK)
    atomicMax(agbits + (b * TB + t0 + tid) * 2 + 1, ssg[tid]);  // ag[].y slot
}

// pass 2: per (b, anchor): argmax over t, thresholds, low-quality flag,
// label + deltas.  2 anchors/thread to amortize per-t LDS broadcasts.
#define P2_K 2
__global__ __launch_bounds__(256) void pass2(const float4* __restrict__ anchors,
                                             const float4* __restrict__ boxes,
                                             const float2* __restrict__ ag,
                                             const int* __restrict__ labels,
                                             float* __restrict__ out, int A) {
  int b = blockIdx.y;
  __shared__ float4 sb[TB];
  __shared__ float2 sag[TB];   // {area, gmax}
  __shared__ int    sl[TB];
  int tid = threadIdx.x;
  if (tid < TB) {
    sb[tid]  = boxes[b * TB + tid];
    sag[tid] = ag[b * TB + tid];
    sl[tid]  = labels[b * TB + tid];
  }
  __syncthreads();

  int a0 = blockIdx.x * (P2_K * 256) + tid;
  float4 av[P2_K];
  float aar[P2_K], best[P2_K];
  int mid[P2_K];
  bool high[P2_K];
#pragma unroll
  for (int k = 0; k < P2_K; ++k) {
    int a = a0 + k * 256;
    if (a > A - 1) a = A - 1;  // compute on dup; store is guarded below
    av[k]  = anchors[a];
    aar[k] = (av[k].z - av[k].x) * (av[k].w - av[k].y);
    best[k] = -1.0f; mid[k] = 0; high[k] = false;
  }

#pragma unroll 4
  for (int t = 0; t < TB; ++t) {
    float4 bb = sb[t];
    float2 agv = sag[t];
#pragma unroll
    for (int k = 0; k < P2_K; ++k) {
      float w = fmaxf(fminf(bb.z, av[k].z) - fmaxf(bb.x, av[k].x), 0.0f);
      float h = fmaxf(fminf(bb.w, av[k].w) - fmaxf(bb.y, av[k].y), 0.0f);
      float inter = w * h;
      float v = inter / ((agv.x + aar[k]) - inter);
      if (v > best[k]) { best[k] = v; mid[k] = t; }  // strict > == first-occurrence
      high[k] = high[k] || (v == agv.y);
    }
  }

#pragma unroll
  for (int k = 0; k < P2_K; ++k) {
    int a = a0 + k * 256;
    if (a >= A) break;

    int lab;
    if (high[k])              lab = 1;
    else if (best[k] >= 0.5f) lab = 1;
    else if (best[k] >= 0.4f) lab = -1;
    else                      lab = 0;

    int out_label;
    if (lab == 1)      out_label = sl[mid[k]];
    else if (lab == 0) out_label = NUM_CLASSES;
    else               out_label = -1;

    out[(size_t)b * A + a] = (float)out_label;

    float4 mb = sb[mid[k]];
    float sw = av[k].z - av[k].x, sh = av[k].w - av[k].y;
    float sx = av[k].x + 0.5f * sw, sy = av[k].y + 0.5f * sh;
    float tw = mb.z - mb.x, th = mb.w - mb.y;
    float tx = mb.x + 0.5f * tw, ty = mb.y + 0.5f * th;
    float4 d;
    d.x = (tx - sx) / sw;
    d.y = (ty - sy) / sh;
    d.z = logf(tw / sw);
    d.w = logf(th / sh);
    *(float4*)(out + (size_t)NB * A + ((size_t)b * A + a) * 4) = d;
  }
}

extern "C" void kernel_launch(void* const* d_in, const int* in_sizes, int n_in,
                              void* d_out, int out_size, void* d_ws, size_t ws_size,
                              hipStream_t stream) {
  const float* anchors    = (const float*)d_in[0];
  const float* tgt_boxes  = (const float*)d_in[1];
  const int*   tgt_labels = (const int*)d_in[2];
  int A = in_sizes[0] / 4;

  float*  ws    = (float*)d_ws;
  float4* boxes = (float4*)ws;                    // NB*TB float4
  float2* ag    = (float2*)(ws + NB * TB * 4);    // NB*TB float2 {area, gmax}
  float*  out   = (float*)d_out;

  pass0<<<2, 256, 0, stream>>>(tgt_boxes, boxes, ag);
  dim3 g1((A + P1_APB - 1) / P1_APB, NB, P1_TSPLIT);
  pass1<<<g1, 256, 0, stream>>>((const float4*)anchors, boxes, ag, (int*)ag, A);
  dim3 g2((A + P2_K * 256 - 1) / (P2_K * 256), NB);
  pass2<<<g2, 256, 0, stream>>>((const float4*)anchors, boxes, ag, tgt_labels, out, A);
}